// Round 1
// baseline (832.501 us; speedup 1.0000x reference)
//
#include <hip/hip_runtime.h>

typedef __attribute__((ext_vector_type(8))) __bf16 bf16x8;
typedef __attribute__((ext_vector_type(4))) __bf16 bf16x4;
typedef __attribute__((ext_vector_type(4))) float f32x4;

#define NB 64
#define LL 512
#define DD 768
#define EPSR 1e-8f

// ---------------- Kernel A: row L2 norms (reciprocal) + zero s0/s1 ----------------
__global__ __launch_bounds__(256) void k_norms(const float* __restrict__ p,
                                               const float* __restrict__ q,
                                               float* __restrict__ rnp,
                                               float* __restrict__ rnq,
                                               float* __restrict__ szero) {
    const int w = threadIdx.x >> 6, lane = threadIdx.x & 63;
    const int row = blockIdx.x * 4 + w;  // 0 .. 2*NB*LL-1
    const float* src = (row < NB * LL) ? (p + (size_t)row * DD)
                                       : (q + (size_t)(row - NB * LL) * DD);
    float s = 0.f;
#pragma unroll
    for (int k2 = 0; k2 < 3; ++k2) {
        float4 v = *(const float4*)(src + ((size_t)lane + 64 * k2) * 4);
        s += v.x * v.x + v.y * v.y + v.z * v.z + v.w * v.w;
    }
#pragma unroll
    for (int m = 1; m < 64; m <<= 1) s += __shfl_xor(s, m, 64);
    if (lane == 0) {
        float r = 1.f / fmaxf(sqrtf(s), EPSR);
        if (row < NB * LL) rnp[row] = r;
        else               rnq[row - NB * LL] = r;
    }
    // zero the s0/s1 accumulators (contiguous 2*NB*LL floats starting at szero)
    if (threadIdx.x < 4) szero[blockIdx.x * 4 + threadIdx.x] = 0.f;
}

// ---------------- Kernel B: attexp = exp(cos(p_i,q_j)) (bf16), s0 row sums, s1 col sums ----
__global__ __launch_bounds__(256) void k_att(const float* __restrict__ p,
                                             const float* __restrict__ q,
                                             const float* __restrict__ rnp,
                                             const float* __restrict__ rnq,
                                             __bf16* __restrict__ attexp,
                                             float* __restrict__ s0,
                                             float* __restrict__ s1) {
    __shared__ __align__(16) __bf16 As[128 * 40];
    __shared__ __align__(16) __bf16 Bs[128 * 40];
    const int b = blockIdx.y;
    const int it = blockIdx.x >> 2, jt = blockIdx.x & 3;
    const int ibase = it * 128, jbase = jt * 128;
    const int tid = threadIdx.x;
    const int w = tid >> 6, lane = tid & 63;
    const int wr = w >> 1, wc = w & 1;
    const int fr = lane & 15, fs = lane >> 4;
    const int tr = tid >> 3, tc = (tid & 7) * 4;

    f32x4 acc[4][4] = {};
    const float* pb = p + (size_t)(b * LL + ibase) * DD;
    const float* qb = q + (size_t)(b * LL + jbase) * DD;

    for (int k0 = 0; k0 < DD; k0 += 32) {
        __syncthreads();
#pragma unroll
        for (int pass = 0; pass < 4; ++pass) {
            int row = pass * 32 + tr;
            float4 va = *(const float4*)(pb + (size_t)row * DD + k0 + tc);
            bf16x4 ha = { (__bf16)va.x, (__bf16)va.y, (__bf16)va.z, (__bf16)va.w };
            *(bf16x4*)&As[row * 40 + tc] = ha;
            float4 vb = *(const float4*)(qb + (size_t)row * DD + k0 + tc);
            bf16x4 hb = { (__bf16)vb.x, (__bf16)vb.y, (__bf16)vb.z, (__bf16)vb.w };
            *(bf16x4*)&Bs[row * 40 + tc] = hb;
        }
        __syncthreads();
        bf16x8 af[4], bfr[4];
#pragma unroll
        for (int m = 0; m < 4; ++m)
            af[m] = *(const bf16x8*)&As[(wr * 64 + m * 16 + fr) * 40 + fs * 8];
#pragma unroll
        for (int n = 0; n < 4; ++n)
            bfr[n] = *(const bf16x8*)&Bs[(wc * 64 + n * 16 + fr) * 40 + fs * 8];
#pragma unroll
        for (int m = 0; m < 4; ++m)
#pragma unroll
            for (int n = 0; n < 4; ++n)
                acc[m][n] = __builtin_amdgcn_mfma_f32_16x16x32_bf16(af[m], bfr[n], acc[m][n], 0, 0, 0);
    }

    // epilogue: scale to cosine, exp, store bf16, accumulate row/col sums
    float rqv[4];
#pragma unroll
    for (int n = 0; n < 4; ++n) rqv[n] = rnq[b * LL + jbase + wc * 64 + n * 16 + fr];
    float csum[4] = {0.f, 0.f, 0.f, 0.f};
#pragma unroll
    for (int m = 0; m < 4; ++m) {
        int ir0 = ibase + wr * 64 + m * 16 + fs * 4;
        float rpv[4], rsum[4] = {0.f, 0.f, 0.f, 0.f};
#pragma unroll
        for (int r = 0; r < 4; ++r) rpv[r] = rnp[b * LL + ir0 + r];
#pragma unroll
        for (int n = 0; n < 4; ++n) {
            int jc = jbase + wc * 64 + n * 16 + fr;
#pragma unroll
            for (int r = 0; r < 4; ++r) {
                float e = __expf(acc[m][n][r] * rpv[r] * rqv[n]);
                __bf16 eb = (__bf16)e;
                attexp[(size_t)(b * LL + ir0 + r) * LL + jc] = eb;
                float ef = (float)eb;
                rsum[r] += ef;
                csum[n] += ef;
            }
        }
#pragma unroll
        for (int r = 0; r < 4; ++r) {
            float v = rsum[r];
            v += __shfl_xor(v, 1, 64);
            v += __shfl_xor(v, 2, 64);
            v += __shfl_xor(v, 4, 64);
            v += __shfl_xor(v, 8, 64);
            if (fr == 0) atomicAdd(&s0[b * LL + ir0 + r], v);
        }
    }
#pragma unroll
    for (int n = 0; n < 4; ++n) {
        float v = csum[n];
        v += __shfl_xor(v, 16, 64);
        v += __shfl_xor(v, 32, 64);
        if (fs == 0) atomicAdd(&s1[b * LL + jbase + wc * 64 + n * 16 + fr], v);
    }
}

// ---------------- Kernel C: fused double PV GEMM ----------------
// out_p[i,d] = (1/s0[i]) * sum_j attexp[i,j] * q[j,d]
// out_q[i,d] =             sum_j attexp[i,j] * (p[j,d] / s1[j])
__global__ __launch_bounds__(256) void k_pv(const float* __restrict__ p,
                                            const float* __restrict__ q,
                                            const __bf16* __restrict__ attexp,
                                            const float* __restrict__ s0,
                                            const float* __restrict__ s1,
                                            float* __restrict__ outp,
                                            float* __restrict__ outq) {
    __shared__ __align__(16) __bf16 Qt[128 * 40];  // [d][j] transposed V tile (q)
    __shared__ __align__(16) __bf16 Pt[128 * 40];  // [d][j] transposed V tile (p/s1)
    const int b = blockIdx.y;
    const int it = blockIdx.x & 3, dt = blockIdx.x >> 2;
    const int ibase = it * 128, dbase = dt * 128;
    const int tid = threadIdx.x;
    const int w = tid >> 6, lane = tid & 63;
    const int wr = w >> 1, wc = w & 1;
    const int fr = lane & 15, fs = lane >> 4;
    const int sd = tid & 127, sj = tid >> 7;

    f32x4 accp[4][4] = {}, accq[4][4] = {};
    const float* pb = p + (size_t)b * LL * DD;
    const float* qb = q + (size_t)b * LL * DD;
    const __bf16* ab = attexp + (size_t)(b * LL + ibase + wr * 64 + fr) * LL + fs * 8;

    for (int j0 = 0; j0 < LL; j0 += 32) {
        __syncthreads();
#pragma unroll
        for (int pass = 0; pass < 4; ++pass) {
            int jq = sj + pass * 2;      // 0..7
            int jg = j0 + jq * 4;        // global j start within batch
            bf16x4 hq, hp;
#pragma unroll
            for (int jj = 0; jj < 4; ++jj) {
                size_t off = (size_t)(jg + jj) * DD + dbase + sd;
                float qv = qb[off];
                float pv = pb[off];
                float rs = 1.f / s1[b * LL + jg + jj];
                hq[jj] = (__bf16)qv;
                hp[jj] = (__bf16)(pv * rs);
            }
            *(bf16x4*)&Qt[sd * 40 + jq * 4] = hq;
            *(bf16x4*)&Pt[sd * 40 + jq * 4] = hp;
        }
        __syncthreads();
        bf16x8 af[4], bq[4], bp[4];
#pragma unroll
        for (int m = 0; m < 4; ++m) af[m] = *(const bf16x8*)(ab + (size_t)m * 16 * LL + j0);
#pragma unroll
        for (int n = 0; n < 4; ++n) {
            bq[n] = *(const bf16x8*)&Qt[(wc * 64 + n * 16 + fr) * 40 + fs * 8];
            bp[n] = *(const bf16x8*)&Pt[(wc * 64 + n * 16 + fr) * 40 + fs * 8];
        }
#pragma unroll
        for (int m = 0; m < 4; ++m)
#pragma unroll
            for (int n = 0; n < 4; ++n) {
                accp[m][n] = __builtin_amdgcn_mfma_f32_16x16x32_bf16(af[m], bq[n], accp[m][n], 0, 0, 0);
                accq[m][n] = __builtin_amdgcn_mfma_f32_16x16x32_bf16(af[m], bp[n], accq[m][n], 0, 0, 0);
            }
    }

#pragma unroll
    for (int m = 0; m < 4; ++m) {
        int ir0 = ibase + wr * 64 + m * 16 + fs * 4;
        float rs0[4];
#pragma unroll
        for (int r = 0; r < 4; ++r) rs0[r] = 1.f / s0[b * LL + ir0 + r];
#pragma unroll
        for (int n = 0; n < 4; ++n) {
            int dc = dbase + wc * 64 + n * 16 + fr;
#pragma unroll
            for (int r = 0; r < 4; ++r) {
                size_t o = (size_t)(b * LL + ir0 + r) * DD + dc;
                outp[o] = accp[m][n][r] * rs0[r];
                outq[o] = accq[m][n][r];
            }
        }
    }
}

extern "C" void kernel_launch(void* const* d_in, const int* in_sizes, int n_in,
                              void* d_out, int out_size, void* d_ws, size_t ws_size,
                              hipStream_t stream) {
    const float* p = (const float*)d_in[0];
    const float* q = (const float*)d_in[1];
    float* outp = (float*)d_out;
    float* outq = outp + (size_t)NB * LL * DD;

    char* ws = (char*)d_ws;
    __bf16* attexp = (__bf16*)ws;                                   // 64*512*512*2 = 32 MiB
    float* rnp = (float*)(ws + (size_t)NB * LL * LL * 2);           // NB*LL floats
    float* rnq = rnp + NB * LL;
    float* s0  = rnq + NB * LL;
    float* s1  = s0 + NB * LL;

    k_norms<<<dim3((2 * NB * LL) / 4), 256, 0, stream>>>(p, q, rnp, rnq, s0);
    k_att<<<dim3(16, NB), 256, 0, stream>>>(p, q, rnp, rnq, attexp, s0, s1);
    k_pv<<<dim3(24, NB), 256, 0, stream>>>(p, q, attexp, s0, s1, outp, outq);
}

// Round 4
// 596.413 us; speedup vs baseline: 1.3958x; 1.3958x over previous
//
#include <hip/hip_runtime.h>

typedef __attribute__((ext_vector_type(8))) __bf16 bf16x8;
typedef __attribute__((ext_vector_type(4))) __bf16 bf16x4;
typedef __attribute__((ext_vector_type(4))) float f32x4;

#define NB 64
#define LL 512
#define DD 768
#define EPSR 1e-8f

__device__ __forceinline__ void gload16(const void* g, void* l) {
    __builtin_amdgcn_global_load_lds(
        (const __attribute__((address_space(1))) unsigned int*)g,
        (__attribute__((address_space(3))) unsigned int*)l, 16, 0, 0);
}

__device__ __forceinline__ bf16x8 cvt8(f32x4 a, f32x4 b) {
    bf16x8 r;
    r[0] = (__bf16)a[0]; r[1] = (__bf16)a[1]; r[2] = (__bf16)a[2]; r[3] = (__bf16)a[3];
    r[4] = (__bf16)b[0]; r[5] = (__bf16)b[1]; r[6] = (__bf16)b[2]; r[7] = (__bf16)b[3];
    return r;
}

// ---------------- k_prep (big-ws): rnorms + bf16 transposes pT/qT + zero s0/s1 ----------------
__global__ __launch_bounds__(256) void k_prep(const float* __restrict__ p, const float* __restrict__ q,
                                              __bf16* __restrict__ pT, __bf16* __restrict__ qT,
                                              float* __restrict__ rnp, float* __restrict__ rnq,
                                              float* __restrict__ s0z) {
    __shared__ __bf16 T[64][72];
    const int bid = blockIdx.x;
    const int mat = bid >> 9;
    const int rem = bid & 511;
    const int b = rem >> 3, ch = rem & 7;
    const float* src = (mat ? q : p) + ((size_t)b * LL + ch * 64) * DD;
    __bf16* dT = (mat ? qT : pT) + (size_t)b * DD * LL + ch * 64;
    const int tid = threadIdx.x;
    const int r = tid >> 2, cs = (tid & 3) * 16;
    float ss = 0.f;
    for (int d0 = 0; d0 < DD; d0 += 64) {
        float4 v[4];
#pragma unroll
        for (int k = 0; k < 4; ++k) v[k] = *(const float4*)(src + (size_t)r * DD + d0 + cs + k * 4);
#pragma unroll
        for (int k = 0; k < 4; ++k) ss += v[k].x * v[k].x + v[k].y * v[k].y + v[k].z * v[k].z + v[k].w * v[k].w;
        __syncthreads();
#pragma unroll
        for (int k = 0; k < 4; ++k) {
            bf16x4 h = { (__bf16)v[k].x, (__bf16)v[k].y, (__bf16)v[k].z, (__bf16)v[k].w };
            *(bf16x4*)&T[r][cs + k * 4] = h;
        }
        __syncthreads();
        bf16x8 t0, t1;
#pragma unroll
        for (int k = 0; k < 8; ++k) { t0[k] = T[cs + k][r]; t1[k] = T[cs + 8 + k][r]; }
        *(bf16x8*)&dT[(size_t)(d0 + r) * LL + cs] = t0;
        *(bf16x8*)&dT[(size_t)(d0 + r) * LL + cs + 8] = t1;
    }
    ss += __shfl_xor(ss, 1, 64);
    ss += __shfl_xor(ss, 2, 64);
    if ((tid & 3) == 0) {
        float rv = 1.f / fmaxf(sqrtf(ss), EPSR);
        (mat ? rnq : rnp)[b * LL + ch * 64 + r] = rv;
    }
    if (bid < 256) s0z[bid * 256 + tid] = 0.f;
}

// ---------------- k_norms (fallback): row rnorms + zero s0/s1 ----------------
__global__ __launch_bounds__(256) void k_norms(const float* __restrict__ p, const float* __restrict__ q,
                                               float* __restrict__ rnp, float* __restrict__ rnq,
                                               float* __restrict__ szero) {
    const int w = threadIdx.x >> 6, lane = threadIdx.x & 63;
    const int row = blockIdx.x * 4 + w;
    const float* src = (row < NB * LL) ? (p + (size_t)row * DD) : (q + (size_t)(row - NB * LL) * DD);
    float s = 0.f;
#pragma unroll
    for (int k2 = 0; k2 < 3; ++k2) {
        float4 v = *(const float4*)(src + ((size_t)lane + 64 * k2) * 4);
        s += v.x * v.x + v.y * v.y + v.z * v.z + v.w * v.w;
    }
#pragma unroll
    for (int m = 1; m < 64; m <<= 1) s += __shfl_xor(s, m, 64);
    if (lane == 0) {
        float r = 1.f / fmaxf(sqrtf(s), EPSR);
        if (row < NB * LL) rnp[row] = r;
        else               rnq[row - NB * LL] = r;
    }
    if (threadIdx.x < 4) szero[blockIdx.x * 4 + threadIdx.x] = 0.f;
}

// ---------------- k_att (shared): attexp = exp(cos) bf16 + s0/s1 sums ----------------
__global__ __launch_bounds__(256) void k_att(const float* __restrict__ p, const float* __restrict__ q,
                                             const float* __restrict__ rnp, const float* __restrict__ rnq,
                                             __bf16* __restrict__ attexp,
                                             float* __restrict__ s0, float* __restrict__ s1) {
    __shared__ __align__(16) float Af[128 * 32];
    __shared__ __align__(16) float Bf[128 * 32];
    const int b = blockIdx.y;
    const int it = blockIdx.x >> 2, jt = blockIdx.x & 3;
    const int ibase = it * 128, jbase = jt * 128;
    const int tid = threadIdx.x;
    const int w = tid >> 6, lane = tid & 63;
    const int wr = w >> 1, wc = w & 1;
    const int fr = lane & 15, fs = lane >> 4;
    const int srow = tid >> 3, c8 = tid & 7;

    f32x4 acc[4][4] = {};
    const float* pb = p + (size_t)(b * LL + ibase) * DD;
    const float* qb = q + (size_t)(b * LL + jbase) * DD;

    for (int k0 = 0; k0 < DD; k0 += 32) {
#pragma unroll
        for (int ps = 0; ps < 4; ++ps) {
            const int row = ps * 32 + srow;
            const int csw = (c8 ^ (row & 7)) * 4;          // swizzled source col (f32)
            const int lo = (ps * 32 + w * 8) * 32;         // wave-uniform LDS base (f32 elems)
            gload16(pb + (size_t)row * DD + k0 + csw, &Af[lo]);
            gload16(qb + (size_t)row * DD + k0 + csw, &Bf[lo]);
        }
        __syncthreads();
        bf16x8 af[4], bfr[4];
#pragma unroll
        for (int m = 0; m < 4; ++m) {
            const int row = wr * 64 + m * 16 + fr, r7 = row & 7;
            f32x4 u0 = *(const f32x4*)((const char*)Af + row * 128 + (((2 * fs) ^ r7) << 4));
            f32x4 u1 = *(const f32x4*)((const char*)Af + row * 128 + (((2 * fs + 1) ^ r7) << 4));
            af[m] = cvt8(u0, u1);
        }
#pragma unroll
        for (int n = 0; n < 4; ++n) {
            const int row = wc * 64 + n * 16 + fr, r7 = row & 7;
            f32x4 u0 = *(const f32x4*)((const char*)Bf + row * 128 + (((2 * fs) ^ r7) << 4));
            f32x4 u1 = *(const f32x4*)((const char*)Bf + row * 128 + (((2 * fs + 1) ^ r7) << 4));
            bfr[n] = cvt8(u0, u1);
        }
#pragma unroll
        for (int m = 0; m < 4; ++m)
#pragma unroll
            for (int n = 0; n < 4; ++n)
                acc[m][n] = __builtin_amdgcn_mfma_f32_16x16x32_bf16(af[m], bfr[n], acc[m][n], 0, 0, 0);
        __syncthreads();
    }

    float rqv[4];
#pragma unroll
    for (int n = 0; n < 4; ++n) rqv[n] = rnq[b * LL + jbase + wc * 64 + n * 16 + fr];
    float csum[4] = {0.f, 0.f, 0.f, 0.f};
#pragma unroll
    for (int m = 0; m < 4; ++m) {
        int ir0 = ibase + wr * 64 + m * 16 + fs * 4;
        float rpv[4], rsum[4] = {0.f, 0.f, 0.f, 0.f};
#pragma unroll
        for (int r = 0; r < 4; ++r) rpv[r] = rnp[b * LL + ir0 + r];
#pragma unroll
        for (int n = 0; n < 4; ++n) {
            int jc = jbase + wc * 64 + n * 16 + fr;
#pragma unroll
            for (int r = 0; r < 4; ++r) {
                float e = __expf(acc[m][n][r] * rpv[r] * rqv[n]);
                __bf16 eb = (__bf16)e;
                attexp[(size_t)(b * LL + ir0 + r) * LL + jc] = eb;
                float ef = (float)eb;
                rsum[r] += ef;
                csum[n] += ef;
            }
        }
#pragma unroll
        for (int r = 0; r < 4; ++r) {
            float v = rsum[r];
            v += __shfl_xor(v, 1, 64);
            v += __shfl_xor(v, 2, 64);
            v += __shfl_xor(v, 4, 64);
            v += __shfl_xor(v, 8, 64);
            if (fr == 0) atomicAdd(&s0[b * LL + ir0 + r], v);
        }
    }
#pragma unroll
    for (int n = 0; n < 4; ++n) {
        float v = csum[n];
        v += __shfl_xor(v, 16, 64);
        v += __shfl_xor(v, 32, 64);
        if (fs == 0) atomicAdd(&s1[b * LL + jbase + wc * 64 + n * 16 + fr], v);
    }
}

// ---------------- k_pts (big-ws): in-place pT[b][d][j] *= 1/s1[b][j] ----------------
__global__ __launch_bounds__(256) void k_pts(__bf16* __restrict__ pT, const float* __restrict__ s1) {
    const size_t idx = (size_t)blockIdx.x * 256 + threadIdx.x;
    const int b = (int)(idx / 49152);
    const int jseg = ((int)idx & 63) * 8;
    bf16x8 v = *(bf16x8*)(pT + idx * 8);
    const float* s = s1 + b * LL + jseg;
    float4 a0 = *(const float4*)s;
    float4 a1 = *(const float4*)(s + 4);
    v[0] = (__bf16)((float)v[0] / a0.x);
    v[1] = (__bf16)((float)v[1] / a0.y);
    v[2] = (__bf16)((float)v[2] / a0.z);
    v[3] = (__bf16)((float)v[3] / a0.w);
    v[4] = (__bf16)((float)v[4] / a1.x);
    v[5] = (__bf16)((float)v[5] / a1.y);
    v[6] = (__bf16)((float)v[6] / a1.z);
    v[7] = (__bf16)((float)v[7] / a1.w);
    *(bf16x8*)(pT + idx * 8) = v;
}

// ---------------- k_pv (big-ws): dual bf16 GEMM via global_load_lds + XOR swizzle ----------------
__global__ __launch_bounds__(256) void k_pv(const __bf16* __restrict__ attexp,
                                            const __bf16* __restrict__ qT,
                                            const __bf16* __restrict__ pTs,
                                            const float* __restrict__ s0,
                                            float* __restrict__ outp, float* __restrict__ outq) {
    __shared__ __align__(16) __bf16 As[128 * 64];
    __shared__ __align__(16) __bf16 Bq[128 * 64];
    __shared__ __align__(16) __bf16 Bp[128 * 64];
    const int b = blockIdx.y;
    const int it = blockIdx.x & 3, dt = blockIdx.x >> 2;
    const int ibase = it * 128, dbase = dt * 128;
    const int tid = threadIdx.x;
    const int w = tid >> 6, lane = tid & 63;
    const int wr = w >> 1, wc = w & 1;
    const int fr = lane & 15, fs = lane >> 4;
    const int srow = tid >> 3, c8 = tid & 7;

    f32x4 accp[4][4] = {}, accq[4][4] = {};
    const __bf16* Ab = attexp + ((size_t)b * LL + ibase) * LL;
    const __bf16* Qb = qT + ((size_t)b * DD + dbase) * LL;
    const __bf16* Pb = pTs + ((size_t)b * DD + dbase) * LL;

    for (int j0 = 0; j0 < LL; j0 += 64) {
#pragma unroll
        for (int ps = 0; ps < 4; ++ps) {
            const int row = ps * 32 + srow;
            const int csw = (c8 ^ (row & 7)) * 8;      // swizzled source col (bf16)
            const size_t go = (size_t)row * LL + j0 + csw;
            const int lo = (ps * 32 + w * 8) * 64;     // wave-uniform LDS base (bf16 elems)
            gload16(Ab + go, &As[lo]);
            gload16(Qb + go, &Bq[lo]);
            gload16(Pb + go, &Bp[lo]);
        }
        __syncthreads();
#pragma unroll
        for (int kk = 0; kk < 2; ++kk) {
            bf16x8 af[4], bq[4], bp[4];
#pragma unroll
            for (int m = 0; m < 4; ++m) {
                const int row = wr * 64 + m * 16 + fr;
                af[m] = *(const bf16x8*)((const char*)As + row * 128 + (((kk * 4 + fs) ^ (row & 7)) << 4));
            }
#pragma unroll
            for (int n = 0; n < 4; ++n) {
                const int row = wc * 64 + n * 16 + fr;
                const int so = ((kk * 4 + fs) ^ (row & 7)) << 4;
                bq[n] = *(const bf16x8*)((const char*)Bq + row * 128 + so);
                bp[n] = *(const bf16x8*)((const char*)Bp + row * 128 + so);
            }
#pragma unroll
            for (int m = 0; m < 4; ++m)
#pragma unroll
                for (int n = 0; n < 4; ++n) {
                    accp[m][n] = __builtin_amdgcn_mfma_f32_16x16x32_bf16(af[m], bq[n], accp[m][n], 0, 0, 0);
                    accq[m][n] = __builtin_amdgcn_mfma_f32_16x16x32_bf16(af[m], bp[n], accq[m][n], 0, 0, 0);
                }
        }
        __syncthreads();
    }

#pragma unroll
    for (int m = 0; m < 4; ++m) {
        int ir0 = ibase + wr * 64 + m * 16 + fs * 4;
        float rs0[4];
#pragma unroll
        for (int r = 0; r < 4; ++r) rs0[r] = 1.f / s0[b * LL + ir0 + r];
#pragma unroll
        for (int n = 0; n < 4; ++n) {
            int dc = dbase + wc * 64 + n * 16 + fr;
#pragma unroll
            for (int r = 0; r < 4; ++r) {
                size_t o = (size_t)(b * LL + ir0 + r) * DD + dc;
                outp[o] = accp[m][n][r] * rs0[r];
                outq[o] = accq[m][n][r];
            }
        }
    }
}

// ---------------- k_pv_fb (fallback, round-1 proven): reg-staged fp32 ----------------
__global__ __launch_bounds__(256) void k_pv_fb(const float* __restrict__ p,
                                               const float* __restrict__ q,
                                               const __bf16* __restrict__ attexp,
                                               const float* __restrict__ s0,
                                               const float* __restrict__ s1,
                                               float* __restrict__ outp, float* __restrict__ outq) {
    __shared__ __align__(16) __bf16 Qt[128 * 40];
    __shared__ __align__(16) __bf16 Pt[128 * 40];
    const int b = blockIdx.y;
    const int it = blockIdx.x & 3, dt = blockIdx.x >> 2;
    const int ibase = it * 128, dbase = dt * 128;
    const int tid = threadIdx.x;
    const int w = tid >> 6, lane = tid & 63;
    const int wr = w >> 1, wc = w & 1;
    const int fr = lane & 15, fs = lane >> 4;
    const int sd = tid & 127, sj = tid >> 7;

    f32x4 accp[4][4] = {}, accq[4][4] = {};
    const float* pb = p + (size_t)b * LL * DD;
    const float* qb = q + (size_t)b * LL * DD;
    const __bf16* ab = attexp + (size_t)(b * LL + ibase + wr * 64 + fr) * LL + fs * 8;

    for (int j0 = 0; j0 < LL; j0 += 32) {
        __syncthreads();
#pragma unroll
        for (int pass = 0; pass < 4; ++pass) {
            int jq = sj + pass * 2;
            int jg = j0 + jq * 4;
            bf16x4 hq, hp;
#pragma unroll
            for (int jj = 0; jj < 4; ++jj) {
                size_t off = (size_t)(jg + jj) * DD + dbase + sd;
                float qv = qb[off];
                float pv = pb[off];
                float rs = 1.f / s1[b * LL + jg + jj];
                hq[jj] = (__bf16)qv;
                hp[jj] = (__bf16)(pv * rs);
            }
            *(bf16x4*)&Qt[sd * 40 + jq * 4] = hq;
            *(bf16x4*)&Pt[sd * 40 + jq * 4] = hp;
        }
        __syncthreads();
        bf16x8 af[4], bq[4], bp[4];
#pragma unroll
        for (int m = 0; m < 4; ++m) af[m] = *(const bf16x8*)(ab + (size_t)m * 16 * LL + j0);
#pragma unroll
        for (int n = 0; n < 4; ++n) {
            bq[n] = *(const bf16x8*)&Qt[(wc * 64 + n * 16 + fr) * 40 + fs * 8];
            bp[n] = *(const bf16x8*)&Pt[(wc * 64 + n * 16 + fr) * 40 + fs * 8];
        }
#pragma unroll
        for (int m = 0; m < 4; ++m)
#pragma unroll
            for (int n = 0; n < 4; ++n) {
                accp[m][n] = __builtin_amdgcn_mfma_f32_16x16x32_bf16(af[m], bq[n], accp[m][n], 0, 0, 0);
                accq[m][n] = __builtin_amdgcn_mfma_f32_16x16x32_bf16(af[m], bp[n], accq[m][n], 0, 0, 0);
            }
    }

#pragma unroll
    for (int m = 0; m < 4; ++m) {
        int ir0 = ibase + wr * 64 + m * 16 + fs * 4;
        float rs0[4];
#pragma unroll
        for (int r = 0; r < 4; ++r) rs0[r] = 1.f / s0[b * LL + ir0 + r];
#pragma unroll
        for (int n = 0; n < 4; ++n) {
            int dc = dbase + wc * 64 + n * 16 + fr;
#pragma unroll
            for (int r = 0; r < 4; ++r) {
                size_t o = (size_t)(b * LL + ir0 + r) * DD + dc;
                outp[o] = accp[m][n][r] * rs0[r];
                outq[o] = accq[m][n][r];
            }
        }
    }
}

extern "C" void kernel_launch(void* const* d_in, const int* in_sizes, int n_in,
                              void* d_out, int out_size, void* d_ws, size_t ws_size,
                              hipStream_t stream) {
    const float* p = (const float*)d_in[0];
    const float* q = (const float*)d_in[1];
    float* outp = (float*)d_out;
    float* outq = outp + (size_t)NB * LL * DD;

    char* ws = (char*)d_ws;
    const size_t attexp_bytes = (size_t)NB * LL * LL * 2;       // 32 MiB
    const size_t t_elems = (size_t)NB * DD * LL;                // 24M elems (48 MiB each)
    const size_t need = attexp_bytes + 2 * t_elems * 2 + 4 * (size_t)NB * LL * 4 + 1024;

    __bf16* attexp = (__bf16*)ws;

    if (ws_size >= need) {
        __bf16* pT = (__bf16*)(ws + attexp_bytes);
        __bf16* qT = pT + t_elems;
        float* rnp = (float*)(qT + t_elems);
        float* rnq = rnp + NB * LL;
        float* s0  = rnq + NB * LL;
        float* s1  = s0 + NB * LL;
        k_prep<<<dim3(1024), 256, 0, stream>>>(p, q, pT, qT, rnp, rnq, s0);
        k_att<<<dim3(16, NB), 256, 0, stream>>>(p, q, rnp, rnq, attexp, s0, s1);
        k_pts<<<dim3(12288), 256, 0, stream>>>(pT, s1);
        k_pv<<<dim3(24, NB), 256, 0, stream>>>(attexp, qT, pT, s0, outp, outq);
    } else {
        float* rnp = (float*)(ws + attexp_bytes);
        float* rnq = rnp + NB * LL;
        float* s0  = rnq + NB * LL;
        float* s1  = s0 + NB * LL;
        k_norms<<<dim3((2 * NB * LL) / 4), 256, 0, stream>>>(p, q, rnp, rnq, s0);
        k_att<<<dim3(16, NB), 256, 0, stream>>>(p, q, rnp, rnq, attexp, s0, s1);
        k_pv_fb<<<dim3(24, NB), 256, 0, stream>>>(p, q, attexp, s0, s1, outp, outq);
    }
}